// Round 7
// baseline (201.114 us; speedup 1.0000x reference)
//
#include <hip/hip_runtime.h>
#include <hip/hip_bf16.h>
#include <stdint.h>

#define IN_F   4096
#define OUT_F  768
#define OUTB   (OUT_F * 8)       // 6144
#define BATCH  1024
#define SPLITK 4
#define KSPAN  (IN_F / SPLITK)   // 1024
#define KGSPAN (KSPAN / 8)       // 128 k-groups per z-slice
#define NIT    (KSPAN / 64)      // 16 iters of BK=64
#define PLANE  (BATCH * OUT_F)   // 786432 floats
#define PLANE4 (PLANE / 4)
#define EPIBLK 768

typedef short short8  __attribute__((ext_vector_type(8)));
typedef float f32x4   __attribute__((ext_vector_type(4)));

// ws layout (bytes):
//   0        : predp float[4][PLANE]      split-K partial planes (12.58 MB)
//   12582912 : wp    ushort[IN_F*OUT_F]   B packed [kg][n][k%8]   (6.29 MB)
//   18874368 : laT   ushort[BATCH*IN_F]   A packed [kg][m][k%8]   (8.39 MB)
//   27262976 : regpart float[1536]
//   27269120 : sqpart  float[768]
#define WS_WP    12582912
#define WS_LAT   18874368
#define WS_REGP  27262976
#define WS_SQP   27269120

__device__ __forceinline__ ushort f2bf(float f) {
    uint32_t u = __builtin_bit_cast(uint32_t, f);
    u += 0x7FFFu + ((u >> 16) & 1u);
    return (ushort)(u >> 16);
}

__device__ __forceinline__ float waveReduceSum(float v) {
    #pragma unroll
    for (int off = 32; off > 0; off >>= 1) v += __shfl_down(v, off, 64);
    return v;
}

// k_weights: blocks [0,1536): int_weights (bf16 packed [kg][n][k%8]) + reg
// partials. blocks [1536,2048): latent fp32 -> bf16 TRANSPOSED-packed
// laT[kg][m][k%8] so k_gemm A-fragments are single coalesced 16B loads.
__global__ __launch_bounds__(256) void k_weights(const float* __restrict__ w,
                                                 const float* __restrict__ latent,
                                                 ushort* __restrict__ wp,
                                                 ushort* __restrict__ laT,
                                                 float* __restrict__ regpart) {
    if (blockIdx.x >= 1536) {
        // 512 blocks, 131072 threads; thread -> (m = t&1023, 4 consecutive kg).
        // Reads: 128B contiguous per lane (L1-friendly; every HBM byte used once).
        // Writes: lanes m-consecutive -> 1KB coalesced per store instr.
        int t = (blockIdx.x - 1536) * 256 + threadIdx.x;
        int m = t & 1023;
        int kg0 = (t >> 10) << 2;
        const float4* src = (const float4*)(latent + (size_t)m * IN_F + kg0 * 8);
        #pragma unroll
        for (int j = 0; j < 4; j++) {
            float4 x0 = src[2 * j];
            float4 x1 = src[2 * j + 1];
            union { ushort u[8]; uint4 v; } pk;
            pk.u[0] = f2bf(x0.x); pk.u[1] = f2bf(x0.y); pk.u[2] = f2bf(x0.z); pk.u[3] = f2bf(x0.w);
            pk.u[4] = f2bf(x1.x); pk.u[5] = f2bf(x1.y); pk.u[6] = f2bf(x1.z); pk.u[7] = f2bf(x1.w);
            *(uint4*)(laT + (((size_t)(kg0 + j) << 10) + m) * 8) = pk.v;
        }
        return;
    }

    int t  = blockIdx.x * 256 + threadIdx.x;
    int o  = t % OUT_F;
    int i8 = t / OUT_F;
    const float* src = w + (size_t)(i8 * 8) * OUTB + (size_t)o * 8;

    const float P[8] = {1.f, 2.f, 4.f, 8.f, 16.f, 32.f, 64.f, -128.f};
    float regsum = 0.f;
    union { ushort u[8]; uint4 v; } pk;

    #pragma unroll
    for (int r = 0; r < 8; r++) {
        float4 a = *(const float4*)(src + (size_t)r * OUTB);
        float4 b = *(const float4*)(src + (size_t)r * OUTB + 4);
        float x[8] = {a.x, a.y, a.z, a.w, b.x, b.y, b.z, b.w};
        float iw = 0.f;
        #pragma unroll
        for (int j = 0; j < 8; j++) {
            float p = __builtin_amdgcn_rcpf(1.f + __expf(-x[j]));
            iw += p * P[j];
            regsum += fminf(p, 1.f - p);
        }
        pk.u[r] = f2bf(iw);
    }
    *(uint4*)(wp + ((size_t)i8 * OUT_F + o) * 8) = pk.v;

    float ws = waveReduceSum(regsum);
    __shared__ float red[4];
    int lane = threadIdx.x & 63, wv = threadIdx.x >> 6;
    if (lane == 0) red[wv] = ws;
    __syncthreads();
    if (threadIdx.x == 0) regpart[blockIdx.x] = red[0] + red[1] + red[2] + red[3];
}

// k_gemm: NO LDS, NO barriers. Both operands in fragment-ready packed layouts;
// per wave-iter: 8 coalesced 16B global loads (L2/L3-hot) + 8 MFMAs, register
// double-buffered so the compiler pipelines with fine-grained vmcnt.
#define LOAD_SET(A_, B_, it) do {                                              \
    _Pragma("unroll") for (int s_ = 0; s_ < 2; s_++) {                         \
        _Pragma("unroll") for (int f_ = 0; f_ < 2; f_++) {                     \
            A_[s_][f_] = *(const short8*)(aB + (size_t)((it) * 8 + s_ * 4) * 8192 + f_ * 128); \
            B_[s_][f_] = *(const short8*)(bB + (size_t)((it) * 8 + s_ * 4) * 6144 + f_ * 128); \
        } } } while (0)

#define MFMA_SET(A_, B_) do {                                                  \
    _Pragma("unroll") for (int s_ = 0; s_ < 2; s_++)                           \
    _Pragma("unroll") for (int fm_ = 0; fm_ < 2; fm_++)                        \
    _Pragma("unroll") for (int fn_ = 0; fn_ < 2; fn_++)                        \
        acc[fm_][fn_] = __builtin_amdgcn_mfma_f32_16x16x32_bf16(               \
            A_[s_][fm_], B_[s_][fn_], acc[fm_][fn_], 0, 0, 0); } while (0)

__global__ __launch_bounds__(256, 3) void k_gemm(const ushort* __restrict__ laT,
                                                 const ushort* __restrict__ wp,
                                                 float* __restrict__ predp) {
    const int tid  = threadIdx.x;
    const int n0   = blockIdx.x * 64;
    const int m0   = blockIdx.y * 64;
    const int kgb  = blockIdx.z * KGSPAN;
    const int lane = tid & 63, w = tid >> 6;
    const int wm = w >> 1, wn = w & 1;
    const int quad = lane >> 4, l16 = lane & 15;

    f32x4 acc[2][2] = {{{0.f,0.f,0.f,0.f},{0.f,0.f,0.f,0.f}},
                       {{0.f,0.f,0.f,0.f},{0.f,0.f,0.f,0.f}}};

    // fragment base pointers (per-lane):
    //   A frag (s,fm): laT[(kgb + it*8 + s*4 + quad)*1024 + m0+wm*32+fm*16+l16]*8
    //   B frag (s,fn): wp [(kgb + it*8 + s*4 + quad)*768  + n0+wn*32+fn*16+l16]*8
    const ushort* aB = laT + (((size_t)(kgb + quad) << 10) + m0 + wm * 32 + l16) * 8;
    const ushort* bB = wp  + ((size_t)(kgb + quad) * OUT_F + n0 + wn * 32 + l16) * 8;

    short8 a0[2][2], b0[2][2], a1[2][2], b1[2][2];
    LOAD_SET(a0, b0, 0);
    #pragma unroll
    for (int it = 0; it < NIT; it += 2) {
        LOAD_SET(a1, b1, it + 1);
        MFMA_SET(a0, b0);
        if (it + 2 < NIT) LOAD_SET(a0, b0, it + 2);
        MFMA_SET(a1, b1);
    }

    float* plane = predp + (size_t)blockIdx.z * PLANE;
    #pragma unroll
    for (int fm = 0; fm < 2; fm++)
    #pragma unroll
    for (int fn = 0; fn < 2; fn++)
    #pragma unroll
    for (int r = 0; r < 4; r++) {
        int m = m0 + wm * 32 + fm * 16 + quad * 4 + r;
        int n = n0 + wn * 32 + fn * 16 + l16;
        plane[(size_t)m * OUT_F + n] = acc[fm][fn][r];
    }
}

// k_epi: 768 blocks x 256 threads; thread -> 4 consecutive n. Plain-store
// per-block partials. NO atomics, NO fences (R5 lesson).
__global__ __launch_bounds__(256) void k_epi(const float* __restrict__ predp,
                                             const float* __restrict__ tsum,
                                             float* __restrict__ sqpart) {
    int g = blockIdx.x * 256 + threadIdx.x;
    int m = g / (OUT_F / 4);
    int c = g % (OUT_F / 4);
    const float4* pp = (const float4*)predp;
    float4 p0 = pp[g];
    float4 p1 = pp[g + PLANE4];
    float4 p2 = pp[g + 2 * PLANE4];
    float4 p3 = pp[g + 3 * PLANE4];
    float pv[4] = {p0.x + p1.x + p2.x + p3.x, p0.y + p1.y + p2.y + p3.y,
                   p0.z + p1.z + p2.z + p3.z, p0.w + p1.w + p2.w + p3.w};
    const float* ts = tsum + (size_t)m * OUTB + (size_t)c * 32;
    float lsum = 0.f;
    #pragma unroll
    for (int j = 0; j < 4; j++) {
        float4 t0 = *(const float4*)(ts + j * 8);
        float4 t1 = *(const float4*)(ts + j * 8 + 4);
        float isum = t0.x + 2.f * t0.y + 4.f * t0.z + 8.f * t0.w
                   + 16.f * t1.x + 32.f * t1.y + 64.f * t1.z - 128.f * t1.w;
        float d = pv[j] - isum;
        lsum += d * d;
    }
    float wsum = waveReduceSum(lsum);
    __shared__ float red[4];
    if ((threadIdx.x & 63) == 0) red[threadIdx.x >> 6] = wsum;
    __syncthreads();
    if (threadIdx.x == 0)
        sqpart[blockIdx.x] = red[0] + red[1] + red[2] + red[3];
}

// k_fin: 1 block; reduce regpart[1536] + sqpart[768], write the 3 outputs.
__global__ __launch_bounds__(256) void k_fin(const float* __restrict__ regpart,
                                             const float* __restrict__ sqpart,
                                             float* __restrict__ out) {
    int tid = threadIdx.x;
    float r = 0.f, s = 0.f;
    #pragma unroll
    for (int j = 0; j < 6; j++) r += regpart[tid + j * 256];
    #pragma unroll
    for (int j = 0; j < 3; j++) s += sqpart[tid + j * 256];
    r = waveReduceSum(r);
    s = waveReduceSum(s);
    __shared__ float redR[4], redS[4];
    int lane = tid & 63, wv = tid >> 6;
    if (lane == 0) { redR[wv] = r; redS[wv] = s; }
    __syncthreads();
    if (tid == 0) {
        float R = redR[0] + redR[1] + redR[2] + redR[3];
        float S = redS[0] + redS[1] + redS[2] + redS[3];
        float recon = S / ((float)(BATCH * OUT_F) * 255.f * 255.f);
        float reg   = 0.001f * R / (float)((size_t)IN_F * OUTB);
        out[0] = recon + reg;
        out[1] = recon;
        out[2] = reg;
    }
}

extern "C" void kernel_launch(void* const* d_in, const int* in_sizes, int n_in,
                              void* d_out, int out_size, void* d_ws, size_t ws_size,
                              hipStream_t stream) {
    const float* latent = (const float*)d_in[0];   // [1024, 4096]
    const float* tsum   = (const float*)d_in[1];   // [1024, 6144]
    const float* weight = (const float*)d_in[2];   // [4096, 6144]
    float* out      = (float*)d_out;
    float* predp    = (float*)d_ws;
    ushort* wp      = (ushort*)((char*)d_ws + WS_WP);
    ushort* laT     = (ushort*)((char*)d_ws + WS_LAT);
    float* regpart  = (float*)((char*)d_ws + WS_REGP);
    float* sqpart   = (float*)((char*)d_ws + WS_SQP);

    k_weights<<<2048, 256, 0, stream>>>(weight, latent, wp, laT, regpart);
    k_gemm<<<dim3(OUT_F / 64, BATCH / 64, SPLITK), 256, 0, stream>>>(laT, wp, predp);
    k_epi<<<EPIBLK, 256, 0, stream>>>(predp, tsum, sqpart);
    k_fin<<<1, 256, 0, stream>>>(regpart, sqpart, out);
}